// Round 17
// baseline (1805.431 us; speedup 1.0000x reference)
//
#include <hip/hip_runtime.h>
#include <hip/hip_bf16.h>

#define NPTS 20000
#define NE   320000
#define KNNK 16
#define NTILE ((NPTS + 127) / 128)   // 157

typedef __attribute__((ext_vector_type(8))) short bf16x8;
typedef __attribute__((ext_vector_type(4))) float f32x4;

// ---- ws layout (float offsets) ----
#define OFF_X1   0
#define OFF_SQ   (OFF_X1 + NPTS*64)          // 1,280,000 (CSR counts/cursor alias pre-conv)
#define OFF_WB   (OFF_SQ + NPTS)             // 1,300,000
#define WB_W1A  0
#define WB_B1A  384
#define WB_W1BT 448
#define WB_B1B  4544
#define WB_W2A  4608      // (128,64)
#define WB_B2A  12800
#define WB_W2B  12864     // (64,64)
#define WB_B2B  16960
#define WB_WE   17024     // (64,256)
#define WB_BE   33408
#define WB_WP   33664
#define WB_BP   37760
#define WB_WR1  37824
#define WB_BR1  41920
#define WB_WR2  41984
#define WB_BR2  42176
#define WB_TOT  42240
#define OFF_NBR  (OFF_WB + WB_TOT)           // int32, 320,000 (CSR elist alias pre-knn)
#define OFF_OFFS (OFF_NBR + NPTS*KNNK)       // uint32, NPTS+1
#define WS1_TOT  (OFF_OFFS + NPTS + 4)
#define OFF_PK   ((WS1_TOT + 3) & ~3)        // stripe partial keys u32 [NPTS][ns][16]
#define WS_NEED_BYTES ((size_t)WS1_TOT * 4)
#define WS2_BYTES (((size_t)OFF_PK + (size_t)NPTS*2*16) * 4)
#define WS4_BYTES (((size_t)OFF_PK + (size_t)NPTS*4*16) * 4)

__global__ __launch_bounds__(256) void k_out_zero(float* out, int nelem) {
    int i = blockIdx.x * 256 + threadIdx.x;
    if (i < nelem) out[i] = 0.0f;
}

// k_prep also zeroes the CSR counts region (saves a launch).
__global__ __launch_bounds__(256) void k_prep(
    const float* W1a, const float* b1a,
    const float* W1b, const float* b1b,
    const float* W2a, const float* b2a,
    const float* W2b, const float* b2b,
    const float* We,  const float* be,
    const float* Wp,  const float* bp,
    const float* Wr1, const float* br1,
    const float* Wr2, const float* br2,
    float* wb, unsigned int* counts)
{
    int t = blockIdx.x * blockDim.x + threadIdx.x;
    int gs = gridDim.x * blockDim.x;
    for (int i = t; i < NPTS; i += gs) counts[i] = 0u;
    for (int i = t; i < 384;  i += gs) wb[WB_W1A+i] = W1a[i];
    for (int i = t; i < 64;   i += gs) wb[WB_B1A+i] = b1a[i];
    for (int i = t; i < 4096; i += gs) { int j=i>>6, k=i&63; wb[WB_W1BT+i] = W1b[k*64+j]; }
    for (int i = t; i < 64;   i += gs) wb[WB_B1B+i] = b1b[i];
    for (int i = t; i < 8192; i += gs) wb[WB_W2A+i] = W2a[i];
    for (int i = t; i < 64;   i += gs) wb[WB_B2A+i] = b2a[i];
    for (int i = t; i < 4096; i += gs) wb[WB_W2B+i] = W2b[i];
    for (int i = t; i < 64;   i += gs) wb[WB_B2B+i] = b2b[i];
    for (int i = t; i < 16384;i += gs) wb[WB_WE+i]  = We[i];
    for (int i = t; i < 256;  i += gs) wb[WB_BE+i]  = be[i];
    for (int i = t; i < 4096; i += gs) wb[WB_WP+i]  = Wp[i];
    for (int i = t; i < 64;   i += gs) wb[WB_BP+i]  = bp[i];
    for (int i = t; i < 4096; i += gs) wb[WB_WR1+i] = Wr1[i];
    for (int i = t; i < 64;   i += gs) wb[WB_BR1+i] = br1[i];
    for (int i = t; i < 192;  i += gs) wb[WB_WR2+i] = Wr2[i];
    for (int i = t; i < 3;    i += gs) wb[WB_BR2+i] = br2[i];
}

// ---- CSR build ----
__global__ __launch_bounds__(256) void k_hist(const int* __restrict__ ei,
                                              unsigned int* __restrict__ counts) {
    int e = blockIdx.x * 256 + threadIdx.x;
    if (e >= NE) return;
    int d = ei[NE + e];
    d = d < 0 ? 0 : (d >= NPTS ? NPTS-1 : d);
    atomicAdd(&counts[d], 1u);
}

// 256 threads, spans of 79 (79*256 = 20224 >= NPTS).
__global__ __launch_bounds__(256) void k_scan(const unsigned int* __restrict__ counts,
                                              unsigned int* __restrict__ cursor,
                                              unsigned int* __restrict__ offs) {
    __shared__ unsigned int ssum[256];
    __shared__ unsigned int sbase[257];
    int t = threadIdx.x;
    int lo = t * 79;
    int hi = lo + 79; if (hi > NPTS) hi = NPTS;
    if (lo > NPTS) lo = NPTS;
    unsigned int sum = 0;
    for (int i = lo; i < hi; ++i) sum += counts[i];
    ssum[t] = sum;
    __syncthreads();
    if (t == 0) {
        unsigned int run = 0;
        for (int i = 0; i < 256; ++i) { sbase[i] = run; run += ssum[i]; }
        sbase[256] = run;
    }
    __syncthreads();
    unsigned int run = sbase[t];
    for (int i = lo; i < hi; ++i) {
        unsigned int c = counts[i];
        offs[i] = run;
        cursor[i] = run;   // overwrites counts[i] (already read)
        run += c;
    }
    if (t == 0) offs[NPTS] = sbase[256];
}

__global__ __launch_bounds__(256) void k_scatter(const int* __restrict__ ei,
                                                 unsigned int* __restrict__ cursor,
                                                 int* __restrict__ elist) {
    int e = blockIdx.x * 256 + threadIdx.x;
    if (e >= NE) return;
    int d = ei[NE + e];
    d = d < 0 ? 0 : (d >= NPTS ? NPTS-1 : d);
    unsigned int pos = atomicAdd(&cursor[d], 1u);
    elist[pos] = e;
}

__device__ __forceinline__ int clampn(int v) {
    return v < 0 ? 0 : (v >= NPTS ? NPTS-1 : v);
}

// Stage 1 gather v2: W1b column hoisted to 64 VGPRs; 3-stage software pipeline
// on the dependent chain elist -> ei -> dep (each load gets a full iteration).
__global__ __launch_bounds__(64) void k_gather(
    const float* __restrict__ dep, const int* __restrict__ ei,
    const int* __restrict__ elist, const unsigned int* __restrict__ offs,
    const float* __restrict__ W1a, const float* __restrict__ b1a,
    const float* __restrict__ W1b, const float* __restrict__ b1b,
    float* __restrict__ x1)
{
    __shared__ float hbuf[2][64];
    int d = blockIdx.x;
    int t = threadIdx.x;
    unsigned int o0 = offs[d], o1 = offs[d+1];
    float xi0 = dep[d*3+0], xi1 = dep[d*3+1], xi2 = dep[d*3+2];
    float wa0 = W1a[t], wa1 = W1a[64+t], wa2 = W1a[128+t];
    float wa3 = W1a[192+t], wa4 = W1a[256+t], wa5 = W1a[320+t];
    float ba = b1a[t], bb = b1b[t];
    float w1b[64];
#pragma unroll
    for (int j = 0; j < 64; ++j) w1b[j] = W1b[j*64 + t];
    float m = 0.0f;          // empty segment -> 0 (matches ref isfinite fixup)
    int buf = 0;
    if (o0 < o1) {
        unsigned int last = o1 - 1;
        // prologue: edge o0 fully; s for o0+1; eid for o0+2 (index-clamped)
        int e0 = elist[o0];
        int s0 = clampn(ei[e0]);
        float dx0 = dep[s0*3+0] - xi0;
        float dx1 = dep[s0*3+1] - xi1;
        float dx2 = dep[s0*3+2] - xi2;
        unsigned int i1 = o0 + 1 < last ? o0 + 1 : last;
        unsigned int i2 = o0 + 2 < last ? o0 + 2 : last;
        int s_nxt  = clampn(ei[elist[i1]]);
        int eid_n2 = elist[i2];
        for (unsigned int o = o0; o < o1; ++o) {
            // layer 1 for edge o
            float h = ba;
            h = fmaf(xi0, wa0, h); h = fmaf(xi1, wa1, h); h = fmaf(xi2, wa2, h);
            h = fmaf(dx0, wa3, h); h = fmaf(dx1, wa4, h); h = fmaf(dx2, wa5, h);
            h = fmaxf(h, 0.0f);
            hbuf[buf][t] = h;
            __syncthreads();
            // issue next-stage loads (latency overlapped by the GEMV below)
            float ndx0 = dep[s_nxt*3+0] - xi0;
            float ndx1 = dep[s_nxt*3+1] - xi1;
            float ndx2 = dep[s_nxt*3+2] - xi2;
            int ns = ei[eid_n2];
            unsigned int i3 = o + 3 < last ? o + 3 : last;
            int neid = elist[i3];
            // layer 2 GEMV (weights in regs)
            const float* hb = hbuf[buf];
            float z = bb;
#pragma unroll 8
            for (int j = 0; j < 64; ++j) z = fmaf(hb[j], w1b[j], z);
            m = fmaxf(m, z);     // m >= 0 always == max(m, relu(z))
            buf ^= 1;
            dx0 = ndx0; dx1 = ndx1; dx2 = ndx2;
            s_nxt = clampn(ns);
            eid_n2 = neid;
        }
    }
    x1[d*64 + t] = m;
}

// Convert x1 rows fp32 -> [hi bf16 x64 | lo bf16 x64] IN PLACE, and write sq.
__global__ __launch_bounds__(256) void k_conv(float* __restrict__ x1, float* __restrict__ sq) {
    int n = blockIdx.x * 256 + threadIdx.x;
    if (n >= NPTS) return;
    float* base = x1 + n*64;
    float4 r[16];
#pragma unroll
    for (int i = 0; i < 16; ++i) r[i] = ((const float4*)base)[i];
    float s = 0.f;
#pragma unroll
    for (int i = 0; i < 16; ++i) s += r[i].x*r[i].x + r[i].y*r[i].y + r[i].z*r[i].z + r[i].w*r[i].w;
    sq[n] = s;
    unsigned int* hi = (unsigned int*)base;
    unsigned int* lo = (unsigned int*)(base + 32);
#pragma unroll
    for (int j = 0; j < 8; ++j) {
        float v[8] = { r[2*j].x, r[2*j].y, r[2*j].z, r[2*j].w,
                       r[2*j+1].x, r[2*j+1].y, r[2*j+1].z, r[2*j+1].w };
        unsigned int hb[8], lb[8];
#pragma unroll
        for (int e = 0; e < 8; ++e) {
            unsigned int u = __float_as_uint(v[e]);
            hb[e] = (u + 0x7fffu + ((u >> 16) & 1u)) >> 16;           // RNE bf16
            float hf = __uint_as_float(hb[e] << 16);
            float lf = v[e] - hf;
            unsigned int ul = __float_as_uint(lf);
            lb[e] = (ul + 0x7fffu + ((ul >> 16) & 1u)) >> 16;
        }
        uint4 hp, lp;
        hp.x = hb[0] | (hb[1] << 16); hp.y = hb[2] | (hb[3] << 16);
        hp.z = hb[4] | (hb[5] << 16); hp.w = hb[6] | (hb[7] << 16);
        lp.x = lb[0] | (lb[1] << 16); lp.y = lb[2] | (lb[3] << 16);
        lp.z = lb[4] | (lb[5] << 16); lp.w = lb[6] | (lb[7] << 16);
        ((uint4*)hi)[j] = hp;
        ((uint4*)lo)[j] = lp;
    }
}

// Insert key into ascending-sorted 16-list via min/max network.
__device__ __forceinline__ void insk(unsigned int (&s)[16], unsigned int k) {
#pragma unroll
    for (int i = 15; i >= 1; --i) s[i] = min(s[i], max(s[i-1], k));
    s[0] = min(s[0], k);
}

// KNN v11 (unchanged from R16): register-selection MFMA + striping + packed keys.
#define RP  136   // staging row pitch in shorts (272 B)
#define QB  64
__global__ __launch_bounds__(512) void k_knn(
    const float* __restrict__ x1, const float* __restrict__ sqv,
    int* __restrict__ nbr, unsigned int* __restrict__ pk)
{
    __shared__ __align__(16) unsigned short qbuf[QB*RP];        // 17408 B
    __shared__ __align__(16) unsigned char  cbuf_raw[128*RP*2]; // 34816 B (c-tiles / key-dump alias)
    __shared__ float ssq[128];
    unsigned short* cbuf = (unsigned short*)cbuf_raw;           // [128][RP]
    const int t  = threadIdx.x;
    const int n0 = blockIdx.x * QB;
    const int ns = gridDim.y;
    const int tps  = (NTILE + ns - 1) / ns;
    const int tbeg = blockIdx.y * tps;
    const int tend = min(NTILE, tbeg + tps);

    // stage q tile: 64 rows x 256 B (hi|lo)
#pragma unroll
    for (int i = 0; i < 2; ++i) {
        int ch2 = i*512 + t;
        int row = ch2 >> 4, off = ch2 & 15;
        uint4 v = make_uint4(0,0,0,0);
        if (n0 + row < NPTS) v = ((const uint4*)(x1 + (n0+row)*64))[off];
        *(uint4*)&qbuf[row*RP + off*8] = v;
    }
    __syncthreads();

    const int lane15 = t & 15;
    const int quad   = (t >> 4) & 3;
    const int w  = t >> 6;
    const int qs = w & 3;         // query strip of 16
    const int ch = w >> 2;        // candidate half (64)
    bf16x8 Bh[2], Bl[2];
    {
        const unsigned short* qr = &qbuf[(qs*16 + lane15)*RP + quad*8];
        Bh[0] = *(const bf16x8*)(qr);
        Bh[1] = *(const bf16x8*)(qr + 32);
        Bl[0] = *(const bf16x8*)(qr + 64);
        Bl[1] = *(const bf16x8*)(qr + 96);
    }
    int myq = n0 + qs*16 + lane15;
    float sqq = (myq < NPTS) ? sqv[myq] : 0.0f;
    unsigned int sk[16];
#pragma unroll
    for (int m = 0; m < 16; ++m) sk[m] = 0xFFFFFFFFu;

    // prefetch first tile of this stripe (prow = absolute row)
    uint4 pv[4];
    int prow[4], poff[4];
#pragma unroll
    for (int i = 0; i < 4; ++i) {
        int ch2 = i*512 + t;
        prow[i] = tbeg*128 + (ch2 >> 4); poff[i] = ch2 & 15;
        pv[i] = make_uint4(0,0,0,0);
        if (prow[i] < NPTS) pv[i] = ((const uint4*)(x1 + prow[i]*64))[poff[i]];
    }
    float sreg = (t < 128 && tbeg*128 + t < NPTS) ? sqv[tbeg*128 + t] : 1e30f;

    for (int tile = tbeg; tile < tend; ++tile) {
        const int c0 = tile * 128;
        __syncthreads();
#pragma unroll
        for (int i = 0; i < 4; ++i)
            *(uint4*)&cbuf[(prow[i] - c0)*RP + poff[i]*8] = pv[i];
        if (t < 128) ssq[t] = sreg;
        __syncthreads();

        // shared threshold across the query's 4 in-wave lists (stale = looser = safe)
        unsigned int pm  = min(sk[15], (unsigned int)__shfl_xor((int)sk[15], 16));
        unsigned int swv = min(pm, (unsigned int)__shfl_xor((int)pm, 32));

        // prefetch next tile (overlaps MFMA+selection)
        if (tile + 1 < tend) {
            const int c0n = c0 + 128;
#pragma unroll
            for (int i = 0; i < 4; ++i) {
                int row = prow[i] + 128;
                pv[i] = make_uint4(0,0,0,0);
                if (row < NPTS) pv[i] = ((const uint4*)(x1 + row*64))[poff[i]];
                prow[i] = row;
            }
            sreg = (t < 128 && c0n + t < NPTS) ? sqv[c0n + t] : 1e30f;
        }

#pragma unroll
        for (int t4 = 0; t4 < 4; ++t4) {
            const unsigned short* cr = &cbuf[(ch*64 + t4*16 + lane15)*RP + quad*8];
            bf16x8 Ah0 = *(const bf16x8*)(cr);
            bf16x8 Ah1 = *(const bf16x8*)(cr + 32);
            bf16x8 Al0 = *(const bf16x8*)(cr + 64);
            bf16x8 Al1 = *(const bf16x8*)(cr + 96);
            f32x4 acc = (f32x4){0.f,0.f,0.f,0.f};
            acc = __builtin_amdgcn_mfma_f32_16x16x32_bf16(Ah0, Bh[0], acc, 0, 0, 0);
            acc = __builtin_amdgcn_mfma_f32_16x16x32_bf16(Al0, Bh[0], acc, 0, 0, 0);
            acc = __builtin_amdgcn_mfma_f32_16x16x32_bf16(Ah0, Bl[0], acc, 0, 0, 0);
            acc = __builtin_amdgcn_mfma_f32_16x16x32_bf16(Ah1, Bh[1], acc, 0, 0, 0);
            acc = __builtin_amdgcn_mfma_f32_16x16x32_bf16(Al1, Bh[1], acc, 0, 0, 0);
            acc = __builtin_amdgcn_mfma_f32_16x16x32_bf16(Ah1, Bl[1], acc, 0, 0, 0);
            int cbase = ch*64 + t4*16 + quad*4;
            float4 s4 = *(const float4*)&ssq[cbase];   // 16-lane broadcast
            float e0 = fmaxf(fmaf(-2.0f, acc[0], s4.x) + sqq, 0.0f);
            float e1 = fmaxf(fmaf(-2.0f, acc[1], s4.y) + sqq, 0.0f);
            float e2 = fmaxf(fmaf(-2.0f, acc[2], s4.z) + sqq, 0.0f);
            float e3 = fmaxf(fmaf(-2.0f, acc[3], s4.w) + sqq, 0.0f);
            unsigned int cg = (unsigned int)(c0 + cbase);
            unsigned int k0 = (__float_as_uint(e0) & 0xFFFF8000u) | (cg+0u);
            unsigned int k1 = (__float_as_uint(e1) & 0xFFFF8000u) | (cg+1u);
            unsigned int k2 = (__float_as_uint(e2) & 0xFFFF8000u) | (cg+2u);
            unsigned int k3 = (__float_as_uint(e3) & 0xFFFF8000u) | (cg+3u);
            unsigned int mn = min(min(k0,k1), min(k2,k3));
            if (mn < swv) {
                if (k0 < sk[15]) insk(sk, k0);
                if (k1 < sk[15]) insk(sk, k1);
                if (k2 < sk[15]) insk(sk, k2);
                if (k3 < sk[15]) insk(sk, k3);
            }
        }
    }
    __syncthreads();   // frag reads done; cbuf reusable as key dump
    {
        int q = qs*16 + lane15, lid = ch*4 + quad;
        unsigned int* fk = (unsigned int*)cbuf_raw;   // [64][8][17] u32
        int base = q*136 + lid*17;
#pragma unroll
        for (int m = 0; m < 16; ++m) fk[base + m] = sk[m];
    }
    __syncthreads();
    if (t < QB && n0 + t < NPTS) {
        const unsigned int* fk = (const unsigned int*)cbuf_raw;
        int qb = t*136;
        int pr[8] = {0,0,0,0,0,0,0,0};
        int obase = (ns == 1) ? (n0 + t)*16 : ((n0 + t)*ns + blockIdx.y)*16;
        for (int r = 0; r < 16; ++r) {
            unsigned int best = 0xFFFFFFFFu; int bl = 0;
#pragma unroll
            for (int l = 0; l < 8; ++l) {
                unsigned int k = fk[qb + l*17 + pr[l]];
                if (k < best) { best = k; bl = l; }
            }
#pragma unroll
            for (int l = 0; l < 8; ++l) pr[l] += (bl == l) ? 1 : 0;
            if (ns == 1) {
                int idx = (int)(best & 0x7FFFu);
                nbr[obase + r] = idx >= NPTS ? NPTS-1 : idx;
            } else {
                pk[obase + r] = best;
            }
        }
    }
}

// Final exact merge of ns sorted per-stripe top-16 key lists (disjoint idx).
__global__ __launch_bounds__(256) void k_fmerge(
    const unsigned int* __restrict__ pk, int ns, int* __restrict__ nbr)
{
    int q = blockIdx.x * 256 + threadIdx.x;
    if (q >= NPTS) return;
    const unsigned int* fk = pk + q*ns*16;
    int pr[4] = {0,0,0,0};
    for (int r = 0; r < 16; ++r) {
        unsigned int best = 0xFFFFFFFFu; int bl = 0;
        for (int l = 0; l < ns; ++l) {
            unsigned int k = fk[l*16 + pr[l]];
            if (k < best) { best = k; bl = l; }
        }
        pr[bl]++;
        int idx = (int)(best & 0x7FFFu);
        nbr[q*16 + r] = idx >= NPTS ? NPTS-1 : idx;
    }
}

__device__ inline float bf2f(unsigned short u) {
    return __uint_as_float(((unsigned int)u) << 16);
}

// Fused stage-2 MLP + head, v3: weights in registers + neighbor-row prefetch.
__global__ __launch_bounds__(64) void k_fuse(
    const float* __restrict__ x1, const int* __restrict__ nbr,
    const float* __restrict__ wb, float* __restrict__ out)
{
    __shared__ __align__(16) float sxr[64];
    __shared__ __align__(16) float svec[64];
    __shared__ __align__(16) float sx2[64];
    __shared__ int snb[16];
    int n = blockIdx.x;
    int t = threadIdx.x;
    {
        const unsigned short* xr = (const unsigned short*)(x1 + n*64);
        sxr[t] = bf2f(xr[t]) + bf2f(xr[64+t]);
    }
    if (t < 16) snb[t] = nbr[n*16 + t];
    __syncthreads();
    const float* W2a = wb + WB_W2A;
    const float* W2b = wb + WB_W2B;
    const float4* sx4 = (const float4*)sxr;
    const float4* sv4 = (const float4*)svec;
    float wd[64], wz[64];
#pragma unroll
    for (int i = 0; i < 64; ++i) wd[i] = W2a[(64+i)*64 + t];
#pragma unroll
    for (int i = 0; i < 64; ++i) wz[i] = W2b[i*64 + t];
    float A = wb[WB_B2A + t];
#pragma unroll
    for (int i4 = 0; i4 < 16; ++i4) {
        float4 v = sx4[i4];
        const float* wr = W2a + i4*256 + t;
        A = fmaf(v.x, wr[0], A); A = fmaf(v.y, wr[64], A);
        A = fmaf(v.z, wr[128], A); A = fmaf(v.w, wr[192], A);
    }
    float D = 0.0f;
#pragma unroll
    for (int i4 = 0; i4 < 16; ++i4) {
        float4 v = sx4[i4];
        D = fmaf(v.x, wd[i4*4+0], D); D = fmaf(v.y, wd[i4*4+1], D);
        D = fmaf(v.z, wd[i4*4+2], D); D = fmaf(v.w, wd[i4*4+3], D);
    }
    const float AD = A - D;
    const float bz = wb[WB_B2B + t];
    float x2v = 0.0f;
    // prefetch neighbor 0's row halves
    unsigned short ya, yb;
    {
        const unsigned short* yr = (const unsigned short*)(x1 + snb[0]*64);
        ya = yr[t]; yb = yr[64+t];
    }
    for (int k = 0; k < 16; ++k) {
        svec[t] = bf2f(ya) + bf2f(yb);
        __syncthreads();
        // prefetch next neighbor row (overlaps the two GEMVs below)
        if (k + 1 < 16) {
            const unsigned short* yr = (const unsigned short*)(x1 + snb[k+1]*64);
            ya = yr[t]; yb = yr[64+t];
        }
        float h = AD;
#pragma unroll
        for (int i4 = 0; i4 < 16; ++i4) {
            float4 v = sv4[i4];
            h = fmaf(v.x, wd[i4*4+0], h); h = fmaf(v.y, wd[i4*4+1], h);
            h = fmaf(v.z, wd[i4*4+2], h); h = fmaf(v.w, wd[i4*4+3], h);
        }
        h = fmaxf(h, 0.f);
        __syncthreads();
        svec[t] = h;
        __syncthreads();
        float z = bz;
#pragma unroll
        for (int i4 = 0; i4 < 16; ++i4) {
            float4 v = sv4[i4];
            z = fmaf(v.x, wz[i4*4+0], z); z = fmaf(v.y, wz[i4*4+1], z);
            z = fmaf(v.z, wz[i4*4+2], z); z = fmaf(v.w, wz[i4*4+3], z);
        }
        x2v = fmaxf(x2v, fmaxf(z, 0.f));
        __syncthreads();
    }
    sx2[t] = x2v;
    __syncthreads();
    const float4* sx24 = (const float4*)sx2;
    const float* We  = wb + WB_WE;
    const float* Wp  = wb + WB_WP;
    const float* Wr1 = wb + WB_WR1;
    const float* Wr2 = wb + WB_WR2;
    for (int r = 0; r < 4; ++r) {
        float xe = wb[WB_BE + r*64 + t];
#pragma unroll
        for (int i4 = 0; i4 < 16; ++i4) {
            float4 v = sx24[i4];
            const float* wr = We + i4*1024 + r*64 + t;
            xe = fmaf(v.x, wr[0], xe); xe = fmaf(v.y, wr[256], xe);
            xe = fmaf(v.z, wr[512], xe); xe = fmaf(v.w, wr[768], xe);
        }
        svec[t] = xe;
        __syncthreads();
        float ft = wb[WB_BP + t];
#pragma unroll
        for (int i4 = 0; i4 < 16; ++i4) {
            float4 v = sv4[i4];
            const float* wr = Wp + i4*256 + t;
            ft = fmaf(v.x, wr[0], ft); ft = fmaf(v.y, wr[64], ft);
            ft = fmaf(v.z, wr[128], ft); ft = fmaf(v.w, wr[192], ft);
        }
        __syncthreads();
        svec[t] = ft;
        __syncthreads();
        float hh = wb[WB_BR1 + t];
#pragma unroll
        for (int i4 = 0; i4 < 16; ++i4) {
            float4 v = sv4[i4];
            const float* wr = Wr1 + i4*256 + t;
            hh = fmaf(v.x, wr[0], hh); hh = fmaf(v.y, wr[64], hh);
            hh = fmaf(v.z, wr[128], hh); hh = fmaf(v.w, wr[192], hh);
        }
        hh = fmaxf(hh, 0.f);
        __syncthreads();
        svec[t] = hh;
        __syncthreads();
        if (t < 3) {
            float o = wb[WB_BR2 + t];
            for (int i = 0; i < 64; ++i) o = fmaf(svec[i], Wr2[i*3 + t], o);
            int m = r * NPTS + n;
            out[m*3 + t] = o;
        }
        __syncthreads();
    }
}

extern "C" void kernel_launch(void* const* d_in, const int* in_sizes, int n_in,
                              void* d_out, int out_size, void* d_ws, size_t ws_size,
                              hipStream_t stream)
{
    const float* dep = (const float*)d_in[0];
    const float* W1a = (const float*)d_in[1];
    const float* b1a = (const float*)d_in[2];
    const float* W1b = (const float*)d_in[3];
    const float* b1b = (const float*)d_in[4];
    const float* W2a = (const float*)d_in[5];
    const float* b2a = (const float*)d_in[6];
    const float* W2b = (const float*)d_in[7];
    const float* b2b = (const float*)d_in[8];
    const float* We  = (const float*)d_in[9];
    const float* be  = (const float*)d_in[10];
    const float* Wp  = (const float*)d_in[11];
    const float* bp  = (const float*)d_in[12];
    const float* Wr1 = (const float*)d_in[13];
    const float* br1 = (const float*)d_in[14];
    const float* Wr2 = (const float*)d_in[15];
    const float* br2 = (const float*)d_in[16];
    const int* ei = (const int*)d_in[17];

    if (ws_size < WS_NEED_BYTES || d_ws == nullptr) {
        k_out_zero<<<(out_size + 255)/256, 256, 0, stream>>>((float*)d_out, out_size);
        return;
    }

    float* ws   = (float*)d_ws;
    float* x1   = ws + OFF_X1;
    float* sq   = ws + OFF_SQ;
    float* wbuf = ws + OFF_WB;
    int*   nbr  = (int*)(ws + OFF_NBR);
    unsigned int* counts = (unsigned int*)(ws + OFF_SQ);
    int*   elist = (int*)(ws + OFF_NBR);
    unsigned int* offs = (unsigned int*)(ws + OFF_OFFS);

    int ns = (ws_size >= WS4_BYTES) ? 4 : (ws_size >= WS2_BYTES) ? 2 : 1;
    unsigned int* pk = (unsigned int*)(ws + OFF_PK);

    k_prep<<<64, 256, 0, stream>>>(W1a,b1a,W1b,b1b,W2a,b2a,W2b,b2b,We,be,Wp,bp,Wr1,br1,Wr2,br2, wbuf, counts);
    k_hist<<<NE/256, 256, 0, stream>>>(ei, counts);
    k_scan<<<1, 256, 0, stream>>>(counts, counts, offs);
    k_scatter<<<NE/256, 256, 0, stream>>>(ei, counts, elist);
    k_gather<<<NPTS, 64, 0, stream>>>(dep, ei, elist, offs, W1a, b1a, W1b, b1b, x1);
    k_conv<<<(NPTS+255)/256, 256, 0, stream>>>(x1, sq);
    dim3 gk((NPTS + QB - 1)/QB, ns);
    k_knn<<<gk, 512, 0, stream>>>(x1, sq, nbr, pk);
    if (ns > 1) k_fmerge<<<(NPTS + 255)/256, 256, 0, stream>>>(pk, ns, nbr);
    k_fuse<<<NPTS, 64, 0, stream>>>(x1, nbr, wbuf, (float*)d_out);
}

// Round 18
// 1120.420 us; speedup vs baseline: 1.6114x; 1.6114x over previous
//
#include <hip/hip_runtime.h>
#include <hip/hip_bf16.h>

#define NPTS 20000
#define NE   320000
#define KNNK 16
#define NTILE ((NPTS + 127) / 128)   // 157

typedef __attribute__((ext_vector_type(8))) short bf16x8;
typedef __attribute__((ext_vector_type(4))) float f32x4;

// ---- ws layout (float offsets) ----
#define OFF_X1   0
#define OFF_SQ   (OFF_X1 + NPTS*64)          // 1,280,000 (CSR counts/cursor alias pre-conv)
#define OFF_WB   (OFF_SQ + NPTS)             // 1,300,000
#define WB_W1A  0
#define WB_B1A  384
#define WB_W1BT 448
#define WB_B1B  4544
#define WB_W2A  4608      // (128,64)
#define WB_B2A  12800
#define WB_W2B  12864     // (64,64)
#define WB_B2B  16960
#define WB_WE   17024     // (64,256)
#define WB_BE   33408
#define WB_WP   33664
#define WB_BP   37760
#define WB_WR1  37824
#define WB_BR1  41920
#define WB_WR2  41984
#define WB_BR2  42176
#define WB_TOT  42240
#define OFF_NBR  (OFF_WB + WB_TOT)           // int32, 320,000 (CSR elist alias pre-knn)
#define OFF_OFFS (OFF_NBR + NPTS*KNNK)       // uint32, NPTS+1
#define WS1_TOT  (OFF_OFFS + NPTS + 4)
#define OFF_PK   ((WS1_TOT + 3) & ~3)        // stripe partial keys u32 [NPTS][ns][16]
#define WS_NEED_BYTES ((size_t)WS1_TOT * 4)
#define WS2_BYTES (((size_t)OFF_PK + (size_t)NPTS*2*16) * 4)
#define WS4_BYTES (((size_t)OFF_PK + (size_t)NPTS*4*16) * 4)

__global__ __launch_bounds__(256) void k_out_zero(float* out, int nelem) {
    int i = blockIdx.x * 256 + threadIdx.x;
    if (i < nelem) out[i] = 0.0f;
}

// k_prep also zeroes the CSR counts region (saves a launch).
__global__ __launch_bounds__(256) void k_prep(
    const float* W1a, const float* b1a,
    const float* W1b, const float* b1b,
    const float* W2a, const float* b2a,
    const float* W2b, const float* b2b,
    const float* We,  const float* be,
    const float* Wp,  const float* bp,
    const float* Wr1, const float* br1,
    const float* Wr2, const float* br2,
    float* wb, unsigned int* counts)
{
    int t = blockIdx.x * blockDim.x + threadIdx.x;
    int gs = gridDim.x * blockDim.x;
    for (int i = t; i < NPTS; i += gs) counts[i] = 0u;
    for (int i = t; i < 384;  i += gs) wb[WB_W1A+i] = W1a[i];
    for (int i = t; i < 64;   i += gs) wb[WB_B1A+i] = b1a[i];
    for (int i = t; i < 4096; i += gs) { int j=i>>6, k=i&63; wb[WB_W1BT+i] = W1b[k*64+j]; }
    for (int i = t; i < 64;   i += gs) wb[WB_B1B+i] = b1b[i];
    for (int i = t; i < 8192; i += gs) wb[WB_W2A+i] = W2a[i];
    for (int i = t; i < 64;   i += gs) wb[WB_B2A+i] = b2a[i];
    for (int i = t; i < 4096; i += gs) wb[WB_W2B+i] = W2b[i];
    for (int i = t; i < 64;   i += gs) wb[WB_B2B+i] = b2b[i];
    for (int i = t; i < 16384;i += gs) wb[WB_WE+i]  = We[i];
    for (int i = t; i < 256;  i += gs) wb[WB_BE+i]  = be[i];
    for (int i = t; i < 4096; i += gs) wb[WB_WP+i]  = Wp[i];
    for (int i = t; i < 64;   i += gs) wb[WB_BP+i]  = bp[i];
    for (int i = t; i < 4096; i += gs) wb[WB_WR1+i] = Wr1[i];
    for (int i = t; i < 64;   i += gs) wb[WB_BR1+i] = br1[i];
    for (int i = t; i < 192;  i += gs) wb[WB_WR2+i] = Wr2[i];
    for (int i = t; i < 3;    i += gs) wb[WB_BR2+i] = br2[i];
}

// ---- CSR build ----
__global__ __launch_bounds__(256) void k_hist(const int* __restrict__ ei,
                                              unsigned int* __restrict__ counts) {
    int e = blockIdx.x * 256 + threadIdx.x;
    if (e >= NE) return;
    int d = ei[NE + e];
    d = d < 0 ? 0 : (d >= NPTS ? NPTS-1 : d);
    atomicAdd(&counts[d], 1u);
}

// 256 threads, spans of 79 (79*256 = 20224 >= NPTS).
__global__ __launch_bounds__(256) void k_scan(const unsigned int* __restrict__ counts,
                                              unsigned int* __restrict__ cursor,
                                              unsigned int* __restrict__ offs) {
    __shared__ unsigned int ssum[256];
    __shared__ unsigned int sbase[257];
    int t = threadIdx.x;
    int lo = t * 79;
    int hi = lo + 79; if (hi > NPTS) hi = NPTS;
    if (lo > NPTS) lo = NPTS;
    unsigned int sum = 0;
    for (int i = lo; i < hi; ++i) sum += counts[i];
    ssum[t] = sum;
    __syncthreads();
    if (t == 0) {
        unsigned int run = 0;
        for (int i = 0; i < 256; ++i) { sbase[i] = run; run += ssum[i]; }
        sbase[256] = run;
    }
    __syncthreads();
    unsigned int run = sbase[t];
    for (int i = lo; i < hi; ++i) {
        unsigned int c = counts[i];
        offs[i] = run;
        cursor[i] = run;   // overwrites counts[i] (already read)
        run += c;
    }
    if (t == 0) offs[NPTS] = sbase[256];
}

__global__ __launch_bounds__(256) void k_scatter(const int* __restrict__ ei,
                                                 unsigned int* __restrict__ cursor,
                                                 int* __restrict__ elist) {
    int e = blockIdx.x * 256 + threadIdx.x;
    if (e >= NE) return;
    int d = ei[NE + e];
    d = d < 0 ? 0 : (d >= NPTS ? NPTS-1 : d);
    unsigned int pos = atomicAdd(&cursor[d], 1u);
    elist[pos] = e;
}

__device__ __forceinline__ int clampn(int v) {
    return v < 0 ? 0 : (v >= NPTS ? NPTS-1 : v);
}

// Stage 1 gather v3: W1b column in VGPRs (FULLY unrolled GEMV -> constant
// indices -> stays in registers; R17's unroll-8 demoted it to scratch = 2.5 GB
// HBM). 3-stage software pipeline on the dependent chain elist -> ei -> dep.
__global__ __launch_bounds__(64) void k_gather(
    const float* __restrict__ dep, const int* __restrict__ ei,
    const int* __restrict__ elist, const unsigned int* __restrict__ offs,
    const float* __restrict__ W1a, const float* __restrict__ b1a,
    const float* __restrict__ W1b, const float* __restrict__ b1b,
    float* __restrict__ x1)
{
    __shared__ float hbuf[2][64];
    int d = blockIdx.x;
    int t = threadIdx.x;
    unsigned int o0 = offs[d], o1 = offs[d+1];
    float xi0 = dep[d*3+0], xi1 = dep[d*3+1], xi2 = dep[d*3+2];
    float wa0 = W1a[t], wa1 = W1a[64+t], wa2 = W1a[128+t];
    float wa3 = W1a[192+t], wa4 = W1a[256+t], wa5 = W1a[320+t];
    float ba = b1a[t], bb = b1b[t];
    float w1b[64];
#pragma unroll
    for (int j = 0; j < 64; ++j) w1b[j] = W1b[j*64 + t];
    float m = 0.0f;          // empty segment -> 0 (matches ref isfinite fixup)
    int buf = 0;
    if (o0 < o1) {
        unsigned int last = o1 - 1;
        int e0 = elist[o0];
        int s0 = clampn(ei[e0]);
        float dx0 = dep[s0*3+0] - xi0;
        float dx1 = dep[s0*3+1] - xi1;
        float dx2 = dep[s0*3+2] - xi2;
        unsigned int i1 = o0 + 1 < last ? o0 + 1 : last;
        unsigned int i2 = o0 + 2 < last ? o0 + 2 : last;
        int s_nxt  = clampn(ei[elist[i1]]);
        int eid_n2 = elist[i2];
        for (unsigned int o = o0; o < o1; ++o) {
            float h = ba;
            h = fmaf(xi0, wa0, h); h = fmaf(xi1, wa1, h); h = fmaf(xi2, wa2, h);
            h = fmaf(dx0, wa3, h); h = fmaf(dx1, wa4, h); h = fmaf(dx2, wa5, h);
            h = fmaxf(h, 0.0f);
            hbuf[buf][t] = h;
            __syncthreads();
            // issue next-stage loads (latency overlapped by the GEMV below)
            float ndx0 = dep[s_nxt*3+0] - xi0;
            float ndx1 = dep[s_nxt*3+1] - xi1;
            float ndx2 = dep[s_nxt*3+2] - xi2;
            int ns2 = ei[eid_n2];
            unsigned int i3 = o + 3 < last ? o + 3 : last;
            int neid = elist[i3];
            // layer 2 GEMV — FULL unroll, w1b stays in VGPRs
            const float* hb = hbuf[buf];
            float z = bb;
#pragma unroll
            for (int j = 0; j < 64; ++j) z = fmaf(hb[j], w1b[j], z);
            m = fmaxf(m, z);     // m >= 0 always == max(m, relu(z))
            buf ^= 1;
            dx0 = ndx0; dx1 = ndx1; dx2 = ndx2;
            s_nxt = clampn(ns2);
            eid_n2 = neid;
        }
    }
    x1[d*64 + t] = m;
}

// Convert x1 rows fp32 -> [hi bf16 x64 | lo bf16 x64] IN PLACE, and write sq.
__global__ __launch_bounds__(256) void k_conv(float* __restrict__ x1, float* __restrict__ sq) {
    int n = blockIdx.x * 256 + threadIdx.x;
    if (n >= NPTS) return;
    float* base = x1 + n*64;
    float4 r[16];
#pragma unroll
    for (int i = 0; i < 16; ++i) r[i] = ((const float4*)base)[i];
    float s = 0.f;
#pragma unroll
    for (int i = 0; i < 16; ++i) s += r[i].x*r[i].x + r[i].y*r[i].y + r[i].z*r[i].z + r[i].w*r[i].w;
    sq[n] = s;
    unsigned int* hi = (unsigned int*)base;
    unsigned int* lo = (unsigned int*)(base + 32);
#pragma unroll
    for (int j = 0; j < 8; ++j) {
        float v[8] = { r[2*j].x, r[2*j].y, r[2*j].z, r[2*j].w,
                       r[2*j+1].x, r[2*j+1].y, r[2*j+1].z, r[2*j+1].w };
        unsigned int hb[8], lb[8];
#pragma unroll
        for (int e = 0; e < 8; ++e) {
            unsigned int u = __float_as_uint(v[e]);
            hb[e] = (u + 0x7fffu + ((u >> 16) & 1u)) >> 16;           // RNE bf16
            float hf = __uint_as_float(hb[e] << 16);
            float lf = v[e] - hf;
            unsigned int ul = __float_as_uint(lf);
            lb[e] = (ul + 0x7fffu + ((ul >> 16) & 1u)) >> 16;
        }
        uint4 hp, lp;
        hp.x = hb[0] | (hb[1] << 16); hp.y = hb[2] | (hb[3] << 16);
        hp.z = hb[4] | (hb[5] << 16); hp.w = hb[6] | (hb[7] << 16);
        lp.x = lb[0] | (lb[1] << 16); lp.y = lb[2] | (lb[3] << 16);
        lp.z = lb[4] | (lb[5] << 16); lp.w = lb[6] | (lb[7] << 16);
        ((uint4*)hi)[j] = hp;
        ((uint4*)lo)[j] = lp;
    }
}

// Insert key into ascending-sorted 16-list via min/max network.
__device__ __forceinline__ void insk(unsigned int (&s)[16], unsigned int k) {
#pragma unroll
    for (int i = 15; i >= 1; --i) s[i] = min(s[i], max(s[i-1], k));
    s[0] = min(s[0], k);
}

// KNN v11 (unchanged from R16): register-selection MFMA + striping + packed keys.
#define RP  136   // staging row pitch in shorts (272 B)
#define QB  64
__global__ __launch_bounds__(512) void k_knn(
    const float* __restrict__ x1, const float* __restrict__ sqv,
    int* __restrict__ nbr, unsigned int* __restrict__ pk)
{
    __shared__ __align__(16) unsigned short qbuf[QB*RP];        // 17408 B
    __shared__ __align__(16) unsigned char  cbuf_raw[128*RP*2]; // 34816 B (c-tiles / key-dump alias)
    __shared__ float ssq[128];
    unsigned short* cbuf = (unsigned short*)cbuf_raw;           // [128][RP]
    const int t  = threadIdx.x;
    const int n0 = blockIdx.x * QB;
    const int ns = gridDim.y;
    const int tps  = (NTILE + ns - 1) / ns;
    const int tbeg = blockIdx.y * tps;
    const int tend = min(NTILE, tbeg + tps);

    // stage q tile: 64 rows x 256 B (hi|lo)
#pragma unroll
    for (int i = 0; i < 2; ++i) {
        int ch2 = i*512 + t;
        int row = ch2 >> 4, off = ch2 & 15;
        uint4 v = make_uint4(0,0,0,0);
        if (n0 + row < NPTS) v = ((const uint4*)(x1 + (n0+row)*64))[off];
        *(uint4*)&qbuf[row*RP + off*8] = v;
    }
    __syncthreads();

    const int lane15 = t & 15;
    const int quad   = (t >> 4) & 3;
    const int w  = t >> 6;
    const int qs = w & 3;         // query strip of 16
    const int ch = w >> 2;        // candidate half (64)
    bf16x8 Bh[2], Bl[2];
    {
        const unsigned short* qr = &qbuf[(qs*16 + lane15)*RP + quad*8];
        Bh[0] = *(const bf16x8*)(qr);
        Bh[1] = *(const bf16x8*)(qr + 32);
        Bl[0] = *(const bf16x8*)(qr + 64);
        Bl[1] = *(const bf16x8*)(qr + 96);
    }
    int myq = n0 + qs*16 + lane15;
    float sqq = (myq < NPTS) ? sqv[myq] : 0.0f;
    unsigned int sk[16];
#pragma unroll
    for (int m = 0; m < 16; ++m) sk[m] = 0xFFFFFFFFu;

    // prefetch first tile of this stripe (prow = absolute row)
    uint4 pv[4];
    int prow[4], poff[4];
#pragma unroll
    for (int i = 0; i < 4; ++i) {
        int ch2 = i*512 + t;
        prow[i] = tbeg*128 + (ch2 >> 4); poff[i] = ch2 & 15;
        pv[i] = make_uint4(0,0,0,0);
        if (prow[i] < NPTS) pv[i] = ((const uint4*)(x1 + prow[i]*64))[poff[i]];
    }
    float sreg = (t < 128 && tbeg*128 + t < NPTS) ? sqv[tbeg*128 + t] : 1e30f;

    for (int tile = tbeg; tile < tend; ++tile) {
        const int c0 = tile * 128;
        __syncthreads();
#pragma unroll
        for (int i = 0; i < 4; ++i)
            *(uint4*)&cbuf[(prow[i] - c0)*RP + poff[i]*8] = pv[i];
        if (t < 128) ssq[t] = sreg;
        __syncthreads();

        // shared threshold across the query's 4 in-wave lists (stale = looser = safe)
        unsigned int pm  = min(sk[15], (unsigned int)__shfl_xor((int)sk[15], 16));
        unsigned int swv = min(pm, (unsigned int)__shfl_xor((int)pm, 32));

        // prefetch next tile (overlaps MFMA+selection)
        if (tile + 1 < tend) {
            const int c0n = c0 + 128;
#pragma unroll
            for (int i = 0; i < 4; ++i) {
                int row = prow[i] + 128;
                pv[i] = make_uint4(0,0,0,0);
                if (row < NPTS) pv[i] = ((const uint4*)(x1 + row*64))[poff[i]];
                prow[i] = row;
            }
            sreg = (t < 128 && c0n + t < NPTS) ? sqv[c0n + t] : 1e30f;
        }

#pragma unroll
        for (int t4 = 0; t4 < 4; ++t4) {
            const unsigned short* cr = &cbuf[(ch*64 + t4*16 + lane15)*RP + quad*8];
            bf16x8 Ah0 = *(const bf16x8*)(cr);
            bf16x8 Ah1 = *(const bf16x8*)(cr + 32);
            bf16x8 Al0 = *(const bf16x8*)(cr + 64);
            bf16x8 Al1 = *(const bf16x8*)(cr + 96);
            f32x4 acc = (f32x4){0.f,0.f,0.f,0.f};
            acc = __builtin_amdgcn_mfma_f32_16x16x32_bf16(Ah0, Bh[0], acc, 0, 0, 0);
            acc = __builtin_amdgcn_mfma_f32_16x16x32_bf16(Al0, Bh[0], acc, 0, 0, 0);
            acc = __builtin_amdgcn_mfma_f32_16x16x32_bf16(Ah0, Bl[0], acc, 0, 0, 0);
            acc = __builtin_amdgcn_mfma_f32_16x16x32_bf16(Ah1, Bh[1], acc, 0, 0, 0);
            acc = __builtin_amdgcn_mfma_f32_16x16x32_bf16(Al1, Bh[1], acc, 0, 0, 0);
            acc = __builtin_amdgcn_mfma_f32_16x16x32_bf16(Ah1, Bl[1], acc, 0, 0, 0);
            int cbase = ch*64 + t4*16 + quad*4;
            float4 s4 = *(const float4*)&ssq[cbase];   // 16-lane broadcast
            float e0 = fmaxf(fmaf(-2.0f, acc[0], s4.x) + sqq, 0.0f);
            float e1 = fmaxf(fmaf(-2.0f, acc[1], s4.y) + sqq, 0.0f);
            float e2 = fmaxf(fmaf(-2.0f, acc[2], s4.z) + sqq, 0.0f);
            float e3 = fmaxf(fmaf(-2.0f, acc[3], s4.w) + sqq, 0.0f);
            unsigned int cg = (unsigned int)(c0 + cbase);
            unsigned int k0 = (__float_as_uint(e0) & 0xFFFF8000u) | (cg+0u);
            unsigned int k1 = (__float_as_uint(e1) & 0xFFFF8000u) | (cg+1u);
            unsigned int k2 = (__float_as_uint(e2) & 0xFFFF8000u) | (cg+2u);
            unsigned int k3 = (__float_as_uint(e3) & 0xFFFF8000u) | (cg+3u);
            unsigned int mn = min(min(k0,k1), min(k2,k3));
            if (mn < swv) {
                if (k0 < sk[15]) insk(sk, k0);
                if (k1 < sk[15]) insk(sk, k1);
                if (k2 < sk[15]) insk(sk, k2);
                if (k3 < sk[15]) insk(sk, k3);
            }
        }
    }
    __syncthreads();   // frag reads done; cbuf reusable as key dump
    {
        int q = qs*16 + lane15, lid = ch*4 + quad;
        unsigned int* fk = (unsigned int*)cbuf_raw;   // [64][8][17] u32
        int base = q*136 + lid*17;
#pragma unroll
        for (int m = 0; m < 16; ++m) fk[base + m] = sk[m];
    }
    __syncthreads();
    if (t < QB && n0 + t < NPTS) {
        const unsigned int* fk = (const unsigned int*)cbuf_raw;
        int qb = t*136;
        int pr[8] = {0,0,0,0,0,0,0,0};
        int obase = (ns == 1) ? (n0 + t)*16 : ((n0 + t)*ns + blockIdx.y)*16;
        for (int r = 0; r < 16; ++r) {
            unsigned int best = 0xFFFFFFFFu; int bl = 0;
#pragma unroll
            for (int l = 0; l < 8; ++l) {
                unsigned int k = fk[qb + l*17 + pr[l]];
                if (k < best) { best = k; bl = l; }
            }
#pragma unroll
            for (int l = 0; l < 8; ++l) pr[l] += (bl == l) ? 1 : 0;
            if (ns == 1) {
                int idx = (int)(best & 0x7FFFu);
                nbr[obase + r] = idx >= NPTS ? NPTS-1 : idx;
            } else {
                pk[obase + r] = best;
            }
        }
    }
}

// Final exact merge of ns sorted per-stripe top-16 key lists (disjoint idx).
__global__ __launch_bounds__(256) void k_fmerge(
    const unsigned int* __restrict__ pk, int ns, int* __restrict__ nbr)
{
    int q = blockIdx.x * 256 + threadIdx.x;
    if (q >= NPTS) return;
    const unsigned int* fk = pk + q*ns*16;
    int pr[4] = {0,0,0,0};
    for (int r = 0; r < 16; ++r) {
        unsigned int best = 0xFFFFFFFFu; int bl = 0;
        for (int l = 0; l < ns; ++l) {
            unsigned int k = fk[l*16 + pr[l]];
            if (k < best) { best = k; bl = l; }
        }
        pr[bl]++;
        int idx = (int)(best & 0x7FFFu);
        nbr[q*16 + r] = idx >= NPTS ? NPTS-1 : idx;
    }
}

__device__ inline float bf2f(unsigned short u) {
    return __uint_as_float(((unsigned int)u) << 16);
}

// Fused stage-2 MLP + head, v3: weights in registers + neighbor-row prefetch.
__global__ __launch_bounds__(64) void k_fuse(
    const float* __restrict__ x1, const int* __restrict__ nbr,
    const float* __restrict__ wb, float* __restrict__ out)
{
    __shared__ __align__(16) float sxr[64];
    __shared__ __align__(16) float svec[64];
    __shared__ __align__(16) float sx2[64];
    __shared__ int snb[16];
    int n = blockIdx.x;
    int t = threadIdx.x;
    {
        const unsigned short* xr = (const unsigned short*)(x1 + n*64);
        sxr[t] = bf2f(xr[t]) + bf2f(xr[64+t]);
    }
    if (t < 16) snb[t] = nbr[n*16 + t];
    __syncthreads();
    const float* W2a = wb + WB_W2A;
    const float* W2b = wb + WB_W2B;
    const float4* sx4 = (const float4*)sxr;
    const float4* sv4 = (const float4*)svec;
    float wd[64], wz[64];
#pragma unroll
    for (int i = 0; i < 64; ++i) wd[i] = W2a[(64+i)*64 + t];
#pragma unroll
    for (int i = 0; i < 64; ++i) wz[i] = W2b[i*64 + t];
    float A = wb[WB_B2A + t];
#pragma unroll
    for (int i4 = 0; i4 < 16; ++i4) {
        float4 v = sx4[i4];
        const float* wr = W2a + i4*256 + t;
        A = fmaf(v.x, wr[0], A); A = fmaf(v.y, wr[64], A);
        A = fmaf(v.z, wr[128], A); A = fmaf(v.w, wr[192], A);
    }
    float D = 0.0f;
#pragma unroll
    for (int i4 = 0; i4 < 16; ++i4) {
        float4 v = sx4[i4];
        D = fmaf(v.x, wd[i4*4+0], D); D = fmaf(v.y, wd[i4*4+1], D);
        D = fmaf(v.z, wd[i4*4+2], D); D = fmaf(v.w, wd[i4*4+3], D);
    }
    const float AD = A - D;
    const float bz = wb[WB_B2B + t];
    float x2v = 0.0f;
    unsigned short ya, yb;
    {
        const unsigned short* yr = (const unsigned short*)(x1 + snb[0]*64);
        ya = yr[t]; yb = yr[64+t];
    }
    for (int k = 0; k < 16; ++k) {
        svec[t] = bf2f(ya) + bf2f(yb);
        __syncthreads();
        if (k + 1 < 16) {
            const unsigned short* yr = (const unsigned short*)(x1 + snb[k+1]*64);
            ya = yr[t]; yb = yr[64+t];
        }
        float h = AD;
#pragma unroll
        for (int i4 = 0; i4 < 16; ++i4) {
            float4 v = sv4[i4];
            h = fmaf(v.x, wd[i4*4+0], h); h = fmaf(v.y, wd[i4*4+1], h);
            h = fmaf(v.z, wd[i4*4+2], h); h = fmaf(v.w, wd[i4*4+3], h);
        }
        h = fmaxf(h, 0.f);
        __syncthreads();
        svec[t] = h;
        __syncthreads();
        float z = bz;
#pragma unroll
        for (int i4 = 0; i4 < 16; ++i4) {
            float4 v = sv4[i4];
            z = fmaf(v.x, wz[i4*4+0], z); z = fmaf(v.y, wz[i4*4+1], z);
            z = fmaf(v.z, wz[i4*4+2], z); z = fmaf(v.w, wz[i4*4+3], z);
        }
        x2v = fmaxf(x2v, fmaxf(z, 0.f));
        __syncthreads();
    }
    sx2[t] = x2v;
    __syncthreads();
    const float4* sx24 = (const float4*)sx2;
    const float* We  = wb + WB_WE;
    const float* Wp  = wb + WB_WP;
    const float* Wr1 = wb + WB_WR1;
    const float* Wr2 = wb + WB_WR2;
    for (int r = 0; r < 4; ++r) {
        float xe = wb[WB_BE + r*64 + t];
#pragma unroll
        for (int i4 = 0; i4 < 16; ++i4) {
            float4 v = sx24[i4];
            const float* wr = We + i4*1024 + r*64 + t;
            xe = fmaf(v.x, wr[0], xe); xe = fmaf(v.y, wr[256], xe);
            xe = fmaf(v.z, wr[512], xe); xe = fmaf(v.w, wr[768], xe);
        }
        svec[t] = xe;
        __syncthreads();
        float ft = wb[WB_BP + t];
#pragma unroll
        for (int i4 = 0; i4 < 16; ++i4) {
            float4 v = sv4[i4];
            const float* wr = Wp + i4*256 + t;
            ft = fmaf(v.x, wr[0], ft); ft = fmaf(v.y, wr[64], ft);
            ft = fmaf(v.z, wr[128], ft); ft = fmaf(v.w, wr[192], ft);
        }
        __syncthreads();
        svec[t] = ft;
        __syncthreads();
        float hh = wb[WB_BR1 + t];
#pragma unroll
        for (int i4 = 0; i4 < 16; ++i4) {
            float4 v = sv4[i4];
            const float* wr = Wr1 + i4*256 + t;
            hh = fmaf(v.x, wr[0], hh); hh = fmaf(v.y, wr[64], hh);
            hh = fmaf(v.z, wr[128], hh); hh = fmaf(v.w, wr[192], hh);
        }
        hh = fmaxf(hh, 0.f);
        __syncthreads();
        svec[t] = hh;
        __syncthreads();
        if (t < 3) {
            float o = wb[WB_BR2 + t];
            for (int i = 0; i < 64; ++i) o = fmaf(svec[i], Wr2[i*3 + t], o);
            int m = r * NPTS + n;
            out[m*3 + t] = o;
        }
        __syncthreads();
    }
}

extern "C" void kernel_launch(void* const* d_in, const int* in_sizes, int n_in,
                              void* d_out, int out_size, void* d_ws, size_t ws_size,
                              hipStream_t stream)
{
    const float* dep = (const float*)d_in[0];
    const float* W1a = (const float*)d_in[1];
    const float* b1a = (const float*)d_in[2];
    const float* W1b = (const float*)d_in[3];
    const float* b1b = (const float*)d_in[4];
    const float* W2a = (const float*)d_in[5];
    const float* b2a = (const float*)d_in[6];
    const float* W2b = (const float*)d_in[7];
    const float* b2b = (const float*)d_in[8];
    const float* We  = (const float*)d_in[9];
    const float* be  = (const float*)d_in[10];
    const float* Wp  = (const float*)d_in[11];
    const float* bp  = (const float*)d_in[12];
    const float* Wr1 = (const float*)d_in[13];
    const float* br1 = (const float*)d_in[14];
    const float* Wr2 = (const float*)d_in[15];
    const float* br2 = (const float*)d_in[16];
    const int* ei = (const int*)d_in[17];

    if (ws_size < WS_NEED_BYTES || d_ws == nullptr) {
        k_out_zero<<<(out_size + 255)/256, 256, 0, stream>>>((float*)d_out, out_size);
        return;
    }

    float* ws   = (float*)d_ws;
    float* x1   = ws + OFF_X1;
    float* sq   = ws + OFF_SQ;
    float* wbuf = ws + OFF_WB;
    int*   nbr  = (int*)(ws + OFF_NBR);
    unsigned int* counts = (unsigned int*)(ws + OFF_SQ);
    int*   elist = (int*)(ws + OFF_NBR);
    unsigned int* offs = (unsigned int*)(ws + OFF_OFFS);

    int ns = (ws_size >= WS4_BYTES) ? 4 : (ws_size >= WS2_BYTES) ? 2 : 1;
    unsigned int* pk = (unsigned int*)(ws + OFF_PK);

    k_prep<<<64, 256, 0, stream>>>(W1a,b1a,W1b,b1b,W2a,b2a,W2b,b2b,We,be,Wp,bp,Wr1,br1,Wr2,br2, wbuf, counts);
    k_hist<<<NE/256, 256, 0, stream>>>(ei, counts);
    k_scan<<<1, 256, 0, stream>>>(counts, counts, offs);
    k_scatter<<<NE/256, 256, 0, stream>>>(ei, counts, elist);
    k_gather<<<NPTS, 64, 0, stream>>>(dep, ei, elist, offs, W1a, b1a, W1b, b1b, x1);
    k_conv<<<(NPTS+255)/256, 256, 0, stream>>>(x1, sq);
    dim3 gk((NPTS + QB - 1)/QB, ns);
    k_knn<<<gk, 512, 0, stream>>>(x1, sq, nbr, pk);
    if (ns > 1) k_fmerge<<<(NPTS + 255)/256, 256, 0, stream>>>(pk, ns, nbr);
    k_fuse<<<NPTS, 64, 0, stream>>>(x1, nbr, wbuf, (float*)d_out);
}